// Round 1
// baseline (179.584 us; speedup 1.0000x reference)
//
#include <hip/hip_runtime.h>

#define NB 8
#define C 256
#define HW 52
#define P (HW*HW)            // 2704
#define NREG 64
#define NTOPK 4
#define SCALE 0.0625f
#define QK_ELEMS (NB*C*P)    // 5537792

// exact unsigned div helpers (verified ranges)
static __device__ __forceinline__ int d7(int v)  { return (v*9363) >> 16; }   // v <= 3135
static __device__ __forceinline__ int d56(int v) { return (v*18725) >> 20; }  // v <= 3135
static __device__ __forceinline__ int d13(int v) { return (v*10083) >> 17; }  // v <= 675

// ---------------- GEMM: q = W @ x + b (per batch, per proj) --------------
// BM=128 (out ch), BN=64 (pos), BK=16, 256 thr, per-thread 8x4.
__global__ __launch_bounds__(256) void gemm_qk(
    const float* __restrict__ x, const float* __restrict__ y,
    const float* __restrict__ qw, const float* __restrict__ qb,
    const float* __restrict__ kw, const float* __restrict__ kb,
    float* __restrict__ qout, float* __restrict__ kout)
{
    const int z = blockIdx.z;            // b*2 + proj
    const int b = z >> 1, proj = z & 1;
    const float* X = (proj ? y : x) + b*C*P;
    const float* W = proj ? kw : qw;
    const float* Bv = proj ? kb : qb;
    float* O = (proj ? kout : qout) + b*C*P;

    const int n0 = blockIdx.x * 64;
    const int m0 = blockIdx.y * 128;

    __shared__ float As[16][128];   // [k][m]
    __shared__ float Bs[16][64];    // [k][n]

    const int tid = threadIdx.x;
    const int tx = tid & 15, ty = tid >> 4;

    float acc[8][4];
    #pragma unroll
    for (int i = 0; i < 8; i++)
        #pragma unroll
        for (int j = 0; j < 4; j++) acc[i][j] = 0.f;

    const int ar = tid >> 1;           // 0..127
    const int ac = (tid & 1) * 8;      // 0 or 8
    const int br = tid >> 4;           // 0..15
    const int bc = (tid & 15) * 4;     // 0..60
    const bool bvalid = (n0 + bc) < P;

    for (int k0 = 0; k0 < 256; k0 += 16) {
        const float4 a0 = *(const float4*)(W + (m0 + ar)*256 + k0 + ac);
        const float4 a1 = *(const float4*)(W + (m0 + ar)*256 + k0 + ac + 4);
        float4 bvv = make_float4(0.f, 0.f, 0.f, 0.f);
        if (bvalid) bvv = *(const float4*)(X + (k0 + br)*P + n0 + bc);
        __syncthreads();
        As[ac+0][ar] = a0.x; As[ac+1][ar] = a0.y; As[ac+2][ar] = a0.z; As[ac+3][ar] = a0.w;
        As[ac+4][ar] = a1.x; As[ac+5][ar] = a1.y; As[ac+6][ar] = a1.z; As[ac+7][ar] = a1.w;
        *(float4*)&Bs[br][bc] = bvv;
        __syncthreads();
        #pragma unroll
        for (int kk = 0; kk < 16; kk++) {
            const float4 af0 = *(const float4*)&As[kk][ty*8];
            const float4 af1 = *(const float4*)&As[kk][ty*8 + 4];
            const float4 bf  = *(const float4*)&Bs[kk][tx*4];
            const float a[8] = {af0.x, af0.y, af0.z, af0.w, af1.x, af1.y, af1.z, af1.w};
            const float bb[4] = {bf.x, bf.y, bf.z, bf.w};
            #pragma unroll
            for (int i = 0; i < 8; i++)
                #pragma unroll
                for (int j = 0; j < 4; j++)
                    acc[i][j] += a[i] * bb[j];
        }
    }

    if ((n0 + tx*4) < P) {
        #pragma unroll
        for (int i = 0; i < 8; i++) {
            const int m = m0 + ty*8 + i;
            const float bias = Bv[m];
            float4 o;
            o.x = acc[i][0] + bias; o.y = acc[i][1] + bias;
            o.z = acc[i][2] + bias; o.w = acc[i][3] + bias;
            *(float4*)(O + m*P + n0 + tx*4) = o;
        }
    }
}

// ---------------- ceil-mode avg pool 7x7 -> (b,c,64) ----------------
__global__ __launch_bounds__(256) void pool_qk(
    const float* __restrict__ q, const float* __restrict__ k,
    float* __restrict__ qr, float* __restrict__ kr)
{
    const int plane = blockIdx.x*4 + (threadIdx.x >> 6);  // 0..4095
    const int reg = threadIdx.x & 63;
    const int proj = plane >> 11;
    const int bcid = plane & 2047;                         // b*256 + c
    const float* src = (proj ? k : q) + (size_t)bcid * P;
    float* dst = (proj ? kr : qr) + bcid*64 + reg;
    const int jh = reg >> 3, jw = reg & 7;
    const int y0 = jh*7, x0 = jw*7;
    const int ry = min(7, HW - y0), rx = min(7, HW - x0);
    float s = 0.f;
    for (int dy = 0; dy < ry; ++dy) {
        const float* row = src + (y0 + dy)*HW + x0;
        for (int dx = 0; dx < rx; ++dx) s += row[dx];
    }
    *dst = s / (float)(ry*rx);
}

// ---------------- a_r (scaled, transposed store) + top-4 indices ----------------
__global__ __launch_bounds__(64) void ar_topk(
    const float* __restrict__ qr, const float* __restrict__ kr,
    float* __restrict__ arT, int* __restrict__ idx)
{
    const int b = blockIdx.y, i = blockIdx.x;
    const int j = threadIdx.x;   // 0..63
    const float* qcol = qr + b*C*64 + i;
    const float* kcol = kr + b*C*64 + j;
    float dot = 0.f;
    #pragma unroll 8
    for (int c = 0; c < 256; c++) dot += qcol[c*64] * kcol[c*64];
    arT[(b*64 + j)*64 + i] = dot * SCALE;   // arT[b][j][i] = s*a_r[b][i][j]

    float v = dot;
    int my = j;
    #pragma unroll
    for (int t = 0; t < NTOPK; t++) {
        float bv = v; int bi = my;
        #pragma unroll
        for (int off = 32; off >= 1; off >>= 1) {
            const float ov = __shfl_xor(bv, off);
            const int   oi = __shfl_xor(bi, off);
            if (ov > bv || (ov == bv && oi < bi)) { bv = ov; bi = oi; }
        }
        if (j == 0) idx[(b*64 + i)*NTOPK + t] = bi;
        if (my == bi) v = -3.0e38f;
    }
}

// ---------------- vals[b,r,t,k2] = s * <q_seq[b,r,t], k_seq[b, idx[b,r,3], k2]> ----
__global__ __launch_bounds__(256) void vals_kernel(
    const float* __restrict__ q, const float* __restrict__ k,
    const int* __restrict__ idx, float* __restrict__ vals)
{
    const int b = blockIdx.y, r = blockIdx.x;
    const int tid = threadIdx.x;
    if (tid >= NTOPK*49) return;
    const int t = tid / 49, k2 = tid % 49;
    const int g = idx[(b*64 + r)*NTOPK + 3];
    const int qY = (r >> 3)*7;                 // always <= 49 < 52
    const int qX = (r & 7)*7 + t;
    const int kY = (g >> 3)*7 + k2/7;
    const int kX = (g & 7)*7 + k2 % 7;
    float dot = 0.f;
    if (qX < HW && kY < HW && kX < HW) {
        const float* qp = q + (size_t)b*C*P + qY*HW + qX;
        const float* kp = k + (size_t)b*C*P + kY*HW + kX;
        #pragma unroll 8
        for (int c = 0; c < 256; c++) dot += qp[(size_t)c*P] * kp[(size_t)c*P];
    }
    vals[((b*64 + r)*NTOPK + t)*49 + k2] = SCALE * dot;
}

// ---------------- final fill: one block per (b, Y1, X1); 2704 f32 out ----------------
__global__ __launch_bounds__(256) void fill_kernel(
    const float* __restrict__ arT, const float* __restrict__ vals,
    const int* __restrict__ idx, float* __restrict__ out)
{
    const int b = blockIdx.y;
    const int yx = blockIdx.x;            // Y1*52 + X1
    const int Y1 = yx / HW, X1 = yx % HW;
    const int r1 = (Y1/7)*8 + X1/7;
    const int q1 = (Y1%7)*7 + X1%7;
    const int p2 = r1*49 + q1;
    const int yy = p2/56, xx = p2 - 56*yy;
    const int regB = (yy/7)*8 + xx/7;

    __shared__ float acol[64];
    __shared__ float vrow[49];
    const int tid = threadIdx.x;
    if (tid < 64) acol[tid] = arT[(b*64 + regB)*64 + tid];
    int ovr = -1;
    if (q1 < NTOPK) {
        ovr = idx[(b*64 + r1)*NTOPK + q1];
        if (tid < 49) vrow[tid] = vals[((b*64 + r1)*NTOPK + q1)*49 + tid];
    }
    __syncthreads();

    float* plane = out + (size_t)(b*P + yx) * P;
    for (int u = tid; u < 676; u += 256) {       // 676 = 52*13 float4 groups
        const int Y2 = d13(u);
        const int g4 = u - Y2*13;
        const int X2b = g4*4;
        const int ry2 = d7(Y2);
        const int my2 = Y2 - ry2*7;
        float res[4];
        #pragma unroll
        for (int j = 0; j < 4; j++) {
            const int X2 = X2b + j;
            const int rx2 = d7(X2);
            const int mx2 = X2 - rx2*7;
            const int r2 = ry2*8 + rx2;
            const int k2 = my2*7 + mx2;
            const int P1 = r2*49 + k2;
            const int Yp = d56(P1);
            const int Xp = P1 - Yp*56;
            const int regA = d7(Yp)*8 + d7(Xp);
            float v = acol[regA];
            if (r2 == ovr) v = vrow[k2];
            res[j] = v;
        }
        float4 o; o.x = res[0]; o.y = res[1]; o.z = res[2]; o.w = res[3];
        *(float4*)(plane + Y2*HW + X2b) = o;
    }
}

extern "C" void kernel_launch(void* const* d_in, const int* in_sizes, int n_in,
                              void* d_out, int out_size, void* d_ws, size_t ws_size,
                              hipStream_t stream)
{
    const float* x  = (const float*)d_in[0];
    const float* y  = (const float*)d_in[1];
    const float* qw = (const float*)d_in[2];
    const float* qb = (const float*)d_in[3];
    const float* kw = (const float*)d_in[4];
    const float* kb = (const float*)d_in[5];
    float* out = (float*)d_out;

    // q,k scratch lives at the front of d_out (44.3 MB << 234 MB out buffer);
    // it is fully consumed by vals_kernel before fill_kernel overwrites d_out.
    float* q = out;
    float* k = out + QK_ELEMS;

    float* ws  = (float*)d_ws;
    float* qr  = ws;                          // NB*C*64 = 131072
    float* kr  = qr + NB*C*64;                // 131072
    float* arT = kr + NB*C*64;                // NB*64*64 = 32768
    float* vls = arT + NB*64*64;              // NB*64*4*49 = 100352
    int*   idx = (int*)(vls + NB*64*NTOPK*49);// NB*64*4 ints

    gemm_qk<<<dim3(43, 2, 16), 256, 0, stream>>>(x, y, qw, qb, kw, kb, q, k);
    pool_qk<<<dim3(1024), 256, 0, stream>>>(q, k, qr, kr);
    ar_topk<<<dim3(64, 8), 64, 0, stream>>>(qr, kr, arT, idx);
    vals_kernel<<<dim3(64, 8), 256, 0, stream>>>(q, k, idx, vls);
    fill_kernel<<<dim3(P, 8), 256, 0, stream>>>(arT, vls, idx, out);
}

// Round 2
// 139.520 us; speedup vs baseline: 1.2872x; 1.2872x over previous
//
#include <hip/hip_runtime.h>

#define NB 8
#define C 256
#define HW 52
#define P (HW*HW)            // 2704
#define NREG 64
#define NTOPK 4
#define SCALE 0.0625f

// exact unsigned div helpers (verified ranges)
static __device__ __forceinline__ int d7(int v)  { return (v*9363) >> 16; }   // v <= 3135
static __device__ __forceinline__ int d56(int v) { return (v*18725) >> 20; }  // v <= 3135
static __device__ __forceinline__ int d13(int v) { return (v*10083) >> 17; }  // v <= 675

// ---------------- prep: M = Wq^T Wk, u = Wk^T qb, v2 = Wq^T kb, c0 = qb.kb ----
__global__ __launch_bounds__(256) void prep_M(
    const float* __restrict__ qw, const float* __restrict__ qb,
    const float* __restrict__ kw, const float* __restrict__ kb,
    float* __restrict__ M, float* __restrict__ u, float* __restrict__ v2,
    float* __restrict__ c0p)
{
    const int tid = threadIdx.x;
    if (blockIdx.x == 64) {
        float ua = 0.f, va = 0.f;
        for (int e = 0; e < 256; e++) {
            ua += qb[e] * kw[e*256 + tid];
            va += kb[e] * qw[e*256 + tid];
        }
        u[tid] = ua; v2[tid] = va;
        if (tid == 0) {
            float c = 0.f;
            for (int e = 0; e < 256; e++) c += qb[e]*kb[e];
            c0p[0] = c;
        }
        return;
    }
    const int cx0 = blockIdx.x * 4;
    __shared__ float wqs[256][4];
    *(float4*)&wqs[tid][0] = *(const float4*)(qw + tid*256 + cx0);
    __syncthreads();
    float a0=0.f, a1=0.f, a2=0.f, a3=0.f;
    #pragma unroll 4
    for (int o = 0; o < 256; o++) {
        const float wk = kw[o*256 + tid];
        const float4 wq = *(const float4*)&wqs[o][0];
        a0 += wq.x*wk; a1 += wq.y*wk; a2 += wq.z*wk; a3 += wq.w*wk;
    }
    M[(cx0+0)*256 + tid] = a0;
    M[(cx0+1)*256 + tid] = a1;
    M[(cx0+2)*256 + tid] = a2;
    M[(cx0+3)*256 + tid] = a3;
}

// ---------------- ceil-mode avg pool 7x7 on x,y -> xr,yr; + xg gather --------
__global__ __launch_bounds__(256) void pool_xy(
    const float* __restrict__ x, const float* __restrict__ y,
    float* __restrict__ xr, float* __restrict__ yr, float* __restrict__ xg)
{
    const int plane = blockIdx.x*4 + (threadIdx.x >> 6);  // 0..4095
    const int reg = threadIdx.x & 63;
    const int proj = plane >> 11;
    const int bcid = plane & 2047;                         // b*256 + c
    const float* src = (proj ? y : x) + (size_t)bcid * P;
    const int jh = reg >> 3, jw = reg & 7;
    const int y0 = jh*7, x0 = jw*7;
    const int ry = min(7, HW - y0), rx = min(7, HW - x0);
    float s = 0.f;
    for (int dy = 0; dy < ry; ++dy) {
        const float* row = src + (y0 + dy)*HW + x0;
        for (int dx = 0; dx < rx; ++dx) s += row[dx];
    }
    ((proj ? yr : xr))[bcid*64 + reg] = s / (float)(ry*rx);
    if (!proj) {
        // gather q-positions: pos = reg*4 + t, value x[y0][x0+t] (0 if col OOB)
        const float* r0 = src + y0*HW + x0;
        float4 g4;
        g4.x = r0[0]; g4.y = r0[1]; g4.z = r0[2];
        g4.w = (x0 + 3 < HW) ? r0[3] : 0.f;
        *(float4*)&xg[bcid*256 + reg*4] = g4;
    }
}

// ---------------- qr/kr = W @ xr/yr + b: per (b,proj), 256x64 @ K=256 --------
__global__ __launch_bounds__(256) void qkr_gemm(
    const float* __restrict__ xr, const float* __restrict__ yr,
    const float* __restrict__ qw, const float* __restrict__ qb,
    const float* __restrict__ kw, const float* __restrict__ kb,
    float* __restrict__ qr, float* __restrict__ kr)
{
    const int bp = blockIdx.y;           // b*2+proj
    const int b = bp >> 1, proj = bp & 1;
    const float* X = (proj ? yr : xr) + b*C*64;
    const float* W = proj ? kw : qw;
    const float* Bv = proj ? kb : qb;
    float* O = (proj ? kr : qr) + b*C*64;
    const int o0 = blockIdx.x * 64;

    __shared__ float As[32][64];   // [k][o]
    __shared__ float Bs[32][64];   // [k][j]
    const int tid = threadIdx.x;
    const int tx = tid & 15, ty = tid >> 4;

    float acc[4][4];
    #pragma unroll
    for (int i = 0; i < 4; i++)
        #pragma unroll
        for (int j = 0; j < 4; j++) acc[i][j] = 0.f;

    const int aor = tid & 63;            // o
    const int akc = (tid >> 6) * 8;      // k base
    const int bkr = tid >> 3;            // k
    const int bjc = (tid & 7) * 8;       // j base

    for (int k0 = 0; k0 < 256; k0 += 32) {
        const float4 w0 = *(const float4*)(W + (o0 + aor)*256 + k0 + akc);
        const float4 w1 = *(const float4*)(W + (o0 + aor)*256 + k0 + akc + 4);
        const float4 x0v = *(const float4*)(X + (k0 + bkr)*64 + bjc);
        const float4 x1v = *(const float4*)(X + (k0 + bkr)*64 + bjc + 4);
        __syncthreads();
        As[akc+0][aor] = w0.x; As[akc+1][aor] = w0.y; As[akc+2][aor] = w0.z; As[akc+3][aor] = w0.w;
        As[akc+4][aor] = w1.x; As[akc+5][aor] = w1.y; As[akc+6][aor] = w1.z; As[akc+7][aor] = w1.w;
        *(float4*)&Bs[bkr][bjc] = x0v;
        *(float4*)&Bs[bkr][bjc+4] = x1v;
        __syncthreads();
        #pragma unroll
        for (int kk = 0; kk < 32; kk++) {
            const float4 a = *(const float4*)&As[kk][ty*4];
            const float4 bb = *(const float4*)&Bs[kk][tx*4];
            const float av[4] = {a.x, a.y, a.z, a.w};
            const float bv2[4] = {bb.x, bb.y, bb.z, bb.w};
            #pragma unroll
            for (int i = 0; i < 4; i++)
                #pragma unroll
                for (int j = 0; j < 4; j++) acc[i][j] += av[i]*bv2[j];
        }
    }
    #pragma unroll
    for (int i = 0; i < 4; i++) {
        const int o = o0 + ty*4 + i;
        const float bias = Bv[o];
        float4 ov;
        ov.x = acc[i][0]+bias; ov.y = acc[i][1]+bias;
        ov.z = acc[i][2]+bias; ov.w = acc[i][3]+bias;
        *(float4*)(O + o*64 + tx*4) = ov;
    }
}

// ---------------- G[b][pos][o] = sum_c xg[b][c][pos]*M[c][o] + u[o] ----------
__global__ __launch_bounds__(256) void g_gemm(
    const float* __restrict__ xg, const float* __restrict__ M,
    const float* __restrict__ u, float* __restrict__ G)
{
    const int b = blockIdx.y;
    const int pt = blockIdx.x >> 2, ot = blockIdx.x & 3;
    const int p0 = pt*64, o0 = ot*64;
    const float* Xg = xg + b*C*256;
    float* Gb = G + b*256*256;

    __shared__ float As[32][64];   // [k][pos]
    __shared__ float Bs[32][64];   // [k][o]
    const int tid = threadIdx.x;
    const int tx = tid & 15, ty = tid >> 4;

    float acc[4][4];
    #pragma unroll
    for (int i = 0; i < 4; i++)
        #pragma unroll
        for (int j = 0; j < 4; j++) acc[i][j] = 0.f;

    const int lkr = tid >> 3;            // k
    const int ljc = (tid & 7) * 8;       // col base

    for (int k0 = 0; k0 < 256; k0 += 32) {
        const float4 a0 = *(const float4*)(Xg + (k0 + lkr)*256 + p0 + ljc);
        const float4 a1 = *(const float4*)(Xg + (k0 + lkr)*256 + p0 + ljc + 4);
        const float4 b0 = *(const float4*)(M + (k0 + lkr)*256 + o0 + ljc);
        const float4 b1 = *(const float4*)(M + (k0 + lkr)*256 + o0 + ljc + 4);
        __syncthreads();
        *(float4*)&As[lkr][ljc] = a0; *(float4*)&As[lkr][ljc+4] = a1;
        *(float4*)&Bs[lkr][ljc] = b0; *(float4*)&Bs[lkr][ljc+4] = b1;
        __syncthreads();
        #pragma unroll
        for (int kk = 0; kk < 32; kk++) {
            const float4 a = *(const float4*)&As[kk][ty*4];
            const float4 bb = *(const float4*)&Bs[kk][tx*4];
            const float av[4] = {a.x, a.y, a.z, a.w};
            const float bv2[4] = {bb.x, bb.y, bb.z, bb.w};
            #pragma unroll
            for (int i = 0; i < 4; i++)
                #pragma unroll
                for (int j = 0; j < 4; j++) acc[i][j] += av[i]*bv2[j];
        }
    }
    const float4 u4 = *(const float4*)(u + o0 + tx*4);
    #pragma unroll
    for (int i = 0; i < 4; i++) {
        float4 ov;
        ov.x = acc[i][0]+u4.x; ov.y = acc[i][1]+u4.y;
        ov.z = acc[i][2]+u4.z; ov.w = acc[i][3]+u4.w;
        *(float4*)(Gb + (p0 + ty*4 + i)*256 + o0 + tx*4) = ov;
    }
}

// ---------------- a_r (scaled, transposed store) + top-4 indices -------------
__global__ __launch_bounds__(64) void ar_topk(
    const float* __restrict__ qr, const float* __restrict__ kr,
    float* __restrict__ arT, int* __restrict__ idx)
{
    const int b = blockIdx.y, i = blockIdx.x;
    const int j = threadIdx.x;   // 0..63
    const float* qcol = qr + b*C*64 + i;
    const float* kcol = kr + b*C*64 + j;
    float dot = 0.f;
    #pragma unroll 8
    for (int c = 0; c < 256; c++) dot += qcol[c*64] * kcol[c*64];
    arT[(b*64 + j)*64 + i] = dot * SCALE;   // arT[b][j][i] = s*a_r[b][i][j]

    float v = dot;
    int my = j;
    #pragma unroll
    for (int t = 0; t < NTOPK; t++) {
        float bv = v; int bi = my;
        #pragma unroll
        for (int off = 32; off >= 1; off >>= 1) {
            const float ov = __shfl_xor(bv, off);
            const int   oi = __shfl_xor(bi, off);
            if (ov > bv || (ov == bv && oi < bi)) { bv = ov; bi = oi; }
        }
        if (j == 0) idx[(b*64 + i)*NTOPK + t] = bi;
        if (my == bi) v = -3.0e38f;
    }
}

// ---------------- vals[b,r,t,k2] = s*(G[b,r*4+t,:].y_kpos + H[b,r*4+t]) ------
__global__ __launch_bounds__(256) void vals_kernel(
    const float* __restrict__ y, const float* __restrict__ G,
    const float* __restrict__ xg, const float* __restrict__ v2,
    const float* __restrict__ c0p, const int* __restrict__ idx,
    float* __restrict__ vals)
{
    const int b = blockIdx.y, r = blockIdx.x;
    const int tid = threadIdx.x;
    __shared__ float Gs[4][256];
    __shared__ float Hs[4];

    // load 4 G rows (coalesced)
    {
        const int t = tid >> 6, c4 = (tid & 63) * 4;
        *(float4*)&Gs[t][c4] = *(const float4*)(G + ((b*256 + r*4 + t)*256) + c4);
    }
    // H[t] = sum_c xg[b][c][r*4+t]*v2[c] + c0 ; warp t computes pos r*4+t
    {
        const int w = tid >> 6, lane = tid & 63;
        const int pos = r*4 + w;
        float acc = 0.f;
        #pragma unroll
        for (int cc = 0; cc < 4; cc++) {
            const int c = lane + cc*64;
            acc += xg[(b*256 + c)*256 + pos] * v2[c];
        }
        #pragma unroll
        for (int off = 32; off >= 1; off >>= 1) acc += __shfl_xor(acc, off);
        if (lane == 0) Hs[w] = acc + c0p[0];
    }
    __syncthreads();

    if (tid >= NTOPK*49) return;
    const int t = tid / 49, k2 = tid - (tid/49)*49;
    const int g = idx[(b*64 + r)*NTOPK + 3];
    const int qX = (r & 7)*7 + t;
    const int kY = (g >> 3)*7 + k2/7;
    const int kX = (g & 7)*7 + k2 % 7;
    float res = 0.f;
    if (qX < HW && kY < HW && kX < HW) {
        const float* yp = y + (size_t)b*C*P + kY*HW + kX;
        float dot = 0.f;
        #pragma unroll 8
        for (int c = 0; c < 256; c++) dot += Gs[t][c] * yp[(size_t)c*P];
        res = SCALE * (dot + Hs[t]);
    }
    vals[((b*64 + r)*NTOPK + t)*49 + k2] = res;
}

// ---------------- final fill: one block per (b, Y1, X1); 2704 f32 out --------
__global__ __launch_bounds__(256) void fill_kernel(
    const float* __restrict__ arT, const float* __restrict__ vals,
    const int* __restrict__ idx, float* __restrict__ out)
{
    const int b = blockIdx.y;
    const int yx = blockIdx.x;            // Y1*52 + X1
    const int Y1 = yx / HW, X1 = yx % HW;
    const int r1 = (Y1/7)*8 + X1/7;
    const int q1 = (Y1%7)*7 + X1%7;
    const int p2 = r1*49 + q1;
    const int yy = p2/56, xx = p2 - 56*yy;
    const int regB = (yy/7)*8 + xx/7;

    __shared__ float acol[64];
    __shared__ float vrow[49];
    const int tid = threadIdx.x;
    if (tid < 64) acol[tid] = arT[(b*64 + regB)*64 + tid];
    int ovr = -1;
    if (q1 < NTOPK) {
        ovr = idx[(b*64 + r1)*NTOPK + q1];
        if (tid < 49) vrow[tid] = vals[((b*64 + r1)*NTOPK + q1)*49 + tid];
    }
    __syncthreads();

    float* plane = out + (size_t)(b*P + yx) * P;
    for (int u = tid; u < 676; u += 256) {       // 676 = 52*13 float4 groups
        const int Y2 = d13(u);
        const int g4 = u - Y2*13;
        const int X2b = g4*4;
        const int ry2 = d7(Y2);
        const int my2 = Y2 - ry2*7;
        float res[4];
        #pragma unroll
        for (int j = 0; j < 4; j++) {
            const int X2 = X2b + j;
            const int rx2 = d7(X2);
            const int mx2 = X2 - rx2*7;
            const int r2 = ry2*8 + rx2;
            const int k2 = my2*7 + mx2;
            const int P1 = r2*49 + k2;
            const int Yp = d56(P1);
            const int Xp = P1 - Yp*56;
            const int regA = d7(Yp)*8 + d7(Xp);
            float v = acol[regA];
            if (r2 == ovr) v = vrow[k2];
            res[j] = v;
        }
        float4 o; o.x = res[0]; o.y = res[1]; o.z = res[2]; o.w = res[3];
        *(float4*)(plane + Y2*HW + X2b) = o;
    }
}

extern "C" void kernel_launch(void* const* d_in, const int* in_sizes, int n_in,
                              void* d_out, int out_size, void* d_ws, size_t ws_size,
                              hipStream_t stream)
{
    const float* x  = (const float*)d_in[0];
    const float* y  = (const float*)d_in[1];
    const float* qw = (const float*)d_in[2];
    const float* qb = (const float*)d_in[3];
    const float* kw = (const float*)d_in[4];
    const float* kb = (const float*)d_in[5];
    float* out = (float*)d_out;

    // Large scratch lives at the front of d_out (~6.3 MB << 234 MB out buffer);
    // all of it is consumed before fill_kernel overwrites d_out.
    float* xr  = out;                 // 8*256*64  = 131072
    float* yr  = xr + 131072;
    float* qr  = yr + 131072;
    float* kr  = qr + 131072;
    float* xg  = kr + 131072;         // 8*256*256 = 524288  [b][c][pos]
    float* G   = xg + 524288;         // 8*256*256 = 524288  [b][pos][o]
    float* M   = G  + 524288;         // 256*256
    float* u   = M  + 65536;          // 256
    float* v2  = u  + 256;            // 256
    float* c0p = v2 + 256;            // 1 (+pad)

    // fill-consumed small arrays stay in d_ws
    float* ws  = (float*)d_ws;
    float* arT = ws;                          // 8*64*64 = 32768
    float* vls = arT + 32768;                 // 8*64*4*49 = 100352
    int*   idx = (int*)(vls + 100352);        // 8*64*4 ints

    prep_M<<<65, 256, 0, stream>>>(qw, qb, kw, kb, M, u, v2, c0p);
    pool_xy<<<1024, 256, 0, stream>>>(x, y, xr, yr, xg);
    qkr_gemm<<<dim3(4, 16), 256, 0, stream>>>(xr, yr, qw, qb, kw, kb, qr, kr);
    g_gemm<<<dim3(16, 8), 256, 0, stream>>>(xg, M, u, G);
    ar_topk<<<dim3(64, 8), 64, 0, stream>>>(qr, kr, arT, idx);
    vals_kernel<<<dim3(64, 8), 256, 0, stream>>>(y, G, xg, v2, c0p, idx, vls);
    fill_kernel<<<dim3(P, 8), 256, 0, stream>>>(arT, vls, idx, out);
}

// Round 3
// 115.889 us; speedup vs baseline: 1.5496x; 1.2039x over previous
//
#include <hip/hip_runtime.h>

#define NB 8
#define C 256
#define HW 52
#define P (HW*HW)            // 2704
#define NREG 64
#define NTOPK 4
#define SCALE 0.0625f

// exact unsigned div helpers (verified ranges)
static __device__ __forceinline__ int d7(int v)  { return (v*9363) >> 16; }   // v <= 3135
static __device__ __forceinline__ int d56(int v) { return (v*18725) >> 20; }  // v <= 3135
static __device__ __forceinline__ int d13(int v) { return (v*10083) >> 17; }  // v <= 675

// ============ K1: blocks 0..1023 pool+gather (LDS-staged, vectorized);
//              blocks 1024..1088 prep (M = Wq^T Wk, u, v2, c0) ==============
__global__ __launch_bounds__(256) void k1_pool_prep(
    const float* __restrict__ x, const float* __restrict__ y,
    const float* __restrict__ qw, const float* __restrict__ qb,
    const float* __restrict__ kw, const float* __restrict__ kb,
    float* __restrict__ xr, float* __restrict__ yr, float* __restrict__ xg,
    float* __restrict__ M, float* __restrict__ u, float* __restrict__ v2,
    float* __restrict__ c0p)
{
    __shared__ float sm[4*P];           // 43.3 KB
    const int tid = threadIdx.x;

    if (blockIdx.x >= 1024) {           // ---- prep path ----
        const int pb = blockIdx.x - 1024;
        if (pb == 64) {
            float ua = 0.f, va = 0.f;
            for (int e = 0; e < 256; e++) {
                ua += qb[e] * kw[e*256 + tid];
                va += kb[e] * qw[e*256 + tid];
            }
            u[tid] = ua; v2[tid] = va;
            if (tid == 0) {
                float c = 0.f;
                for (int e = 0; e < 256; e++) c += qb[e]*kb[e];
                c0p[0] = c;
            }
            return;
        }
        const int cx0 = pb * 4;
        float (*wqs)[4] = (float(*)[4])sm;
        *(float4*)&wqs[tid][0] = *(const float4*)(qw + tid*256 + cx0);
        __syncthreads();
        float a0=0.f, a1=0.f, a2=0.f, a3=0.f;
        #pragma unroll 4
        for (int o = 0; o < 256; o++) {
            const float wk = kw[o*256 + tid];
            const float4 wq = *(const float4*)&wqs[o][0];
            a0 += wq.x*wk; a1 += wq.y*wk; a2 += wq.z*wk; a3 += wq.w*wk;
        }
        M[(cx0+0)*256 + tid] = a0;
        M[(cx0+1)*256 + tid] = a1;
        M[(cx0+2)*256 + tid] = a2;
        M[(cx0+3)*256 + tid] = a3;
        return;
    }

    // ---- pool path: wave w handles plane blockIdx.x*4+w ----
    const int w = tid >> 6, lane = tid & 63;
    const int pl = blockIdx.x*4 + w;
    const int proj = pl >> 11;
    const int bcid = pl & 2047;                     // b*256 + c
    const float* src = (proj ? y : x) + (size_t)bcid * P;
    float* plane = sm + w*P;
    {   // vectorized plane load: 676 float4
        const float4* s4 = (const float4*)src;
        float4* p4 = (float4*)plane;
        for (int g = lane; g < 676; g += 64) p4[g] = s4[g];
    }
    __syncthreads();
    const int jh = lane >> 3, jw = lane & 7;
    const int y0 = jh*7, x0 = jw*7;
    const int ry = min(7, HW - y0), rx = min(7, HW - x0);
    float s = 0.f;
    for (int dy = 0; dy < ry; ++dy) {
        const float* row = plane + (y0 + dy)*HW + x0;
        for (int dx = 0; dx < rx; ++dx) s += row[dx];
    }
    (proj ? yr : xr)[bcid*64 + lane] = s / (float)(ry*rx);
    if (!proj) {
        const float* r0 = plane + y0*HW + x0;
        float4 g4;
        g4.x = r0[0]; g4.y = r0[1]; g4.z = r0[2];
        g4.w = (x0 + 3 < HW) ? r0[3] : 0.f;
        *(float4*)&xg[bcid*256 + lane*4] = g4;
    }
}

// ============ K2: blocks 0..63 qkr_gemm; blocks 64..191 g_gemm ==============
__global__ __launch_bounds__(256) void k2_gemms(
    const float* __restrict__ xr, const float* __restrict__ yr,
    const float* __restrict__ qw, const float* __restrict__ qb,
    const float* __restrict__ kw, const float* __restrict__ kb,
    float* __restrict__ qr, float* __restrict__ kr,
    const float* __restrict__ xg, const float* __restrict__ M,
    const float* __restrict__ u, float* __restrict__ G)
{
    __shared__ float As[32][64];
    __shared__ float Bs[32][64];
    const int tid = threadIdx.x;
    const int tx = tid & 15, ty = tid >> 4;

    float acc[4][4];
    #pragma unroll
    for (int i = 0; i < 4; i++)
        #pragma unroll
        for (int j = 0; j < 4; j++) acc[i][j] = 0.f;

    if (blockIdx.x < 64) {
        // ---- qkr: O[o][j] = sum_k W[o][k]*X[k][j] + b[o] ----
        const int bp = blockIdx.x >> 2;
        const int b = bp >> 1, proj = bp & 1;
        const float* X = (proj ? yr : xr) + b*C*64;
        const float* W = proj ? kw : qw;
        const float* Bv = proj ? kb : qb;
        float* O = (proj ? kr : qr) + b*C*64;
        const int o0 = (blockIdx.x & 3) * 64;

        const int aor = tid & 63;
        const int akc = (tid >> 6) * 8;
        const int bkr = tid >> 3;
        const int bjc = (tid & 7) * 8;

        for (int k0 = 0; k0 < 256; k0 += 32) {
            const float4 w0 = *(const float4*)(W + (o0 + aor)*256 + k0 + akc);
            const float4 w1 = *(const float4*)(W + (o0 + aor)*256 + k0 + akc + 4);
            const float4 x0v = *(const float4*)(X + (k0 + bkr)*64 + bjc);
            const float4 x1v = *(const float4*)(X + (k0 + bkr)*64 + bjc + 4);
            __syncthreads();
            As[akc+0][aor] = w0.x; As[akc+1][aor] = w0.y; As[akc+2][aor] = w0.z; As[akc+3][aor] = w0.w;
            As[akc+4][aor] = w1.x; As[akc+5][aor] = w1.y; As[akc+6][aor] = w1.z; As[akc+7][aor] = w1.w;
            *(float4*)&Bs[bkr][bjc] = x0v;
            *(float4*)&Bs[bkr][bjc+4] = x1v;
            __syncthreads();
            #pragma unroll
            for (int kk = 0; kk < 32; kk++) {
                const float4 a = *(const float4*)&As[kk][ty*4];
                const float4 bb = *(const float4*)&Bs[kk][tx*4];
                const float av[4] = {a.x, a.y, a.z, a.w};
                const float bv[4] = {bb.x, bb.y, bb.z, bb.w};
                #pragma unroll
                for (int i = 0; i < 4; i++)
                    #pragma unroll
                    for (int j = 0; j < 4; j++) acc[i][j] += av[i]*bv[j];
            }
        }
        #pragma unroll
        for (int i = 0; i < 4; i++) {
            const int o = o0 + ty*4 + i;
            const float bias = Bv[o];
            float4 ov;
            ov.x = acc[i][0]+bias; ov.y = acc[i][1]+bias;
            ov.z = acc[i][2]+bias; ov.w = acc[i][3]+bias;
            *(float4*)(O + o*64 + tx*4) = ov;
        }
    } else {
        // ---- G[b][pos][o] = sum_c xg[b][c][pos]*M[c][o] + u[o] ----
        const int id2 = blockIdx.x - 64;
        const int b = id2 >> 4, sub = id2 & 15;
        const int p0 = (sub >> 2)*64, o0 = (sub & 3)*64;
        const float* Xg = xg + b*C*256;
        float* Gb = G + b*256*256;

        const int lkr = tid >> 3;
        const int ljc = (tid & 7) * 8;

        for (int k0 = 0; k0 < 256; k0 += 32) {
            const float4 a0 = *(const float4*)(Xg + (k0 + lkr)*256 + p0 + ljc);
            const float4 a1 = *(const float4*)(Xg + (k0 + lkr)*256 + p0 + ljc + 4);
            const float4 b0 = *(const float4*)(M + (k0 + lkr)*256 + o0 + ljc);
            const float4 b1 = *(const float4*)(M + (k0 + lkr)*256 + o0 + ljc + 4);
            __syncthreads();
            *(float4*)&As[lkr][ljc] = a0; *(float4*)&As[lkr][ljc+4] = a1;
            *(float4*)&Bs[lkr][ljc] = b0; *(float4*)&Bs[lkr][ljc+4] = b1;
            __syncthreads();
            #pragma unroll
            for (int kk = 0; kk < 32; kk++) {
                const float4 a = *(const float4*)&As[kk][ty*4];
                const float4 bb = *(const float4*)&Bs[kk][tx*4];
                const float av[4] = {a.x, a.y, a.z, a.w};
                const float bv[4] = {bb.x, bb.y, bb.z, bb.w};
                #pragma unroll
                for (int i = 0; i < 4; i++)
                    #pragma unroll
                    for (int j = 0; j < 4; j++) acc[i][j] += av[i]*bv[j];
            }
        }
        const float4 u4 = *(const float4*)(u + o0 + tx*4);
        #pragma unroll
        for (int i = 0; i < 4; i++) {
            float4 ov;
            ov.x = acc[i][0]+u4.x; ov.y = acc[i][1]+u4.y;
            ov.z = acc[i][2]+u4.z; ov.w = acc[i][3]+u4.w;
            *(float4*)(Gb + (p0 + ty*4 + i)*256 + o0 + tx*4) = ov;
        }
    }
}

// ============ K3: per (b,r): a_r row + top-4 + vals (LDS-staged y region) ====
__global__ __launch_bounds__(256) void k3_topk_vals(
    const float* __restrict__ y, const float* __restrict__ qr,
    const float* __restrict__ kr, const float* __restrict__ G,
    const float* __restrict__ xg, const float* __restrict__ v2,
    const float* __restrict__ c0p,
    float* __restrict__ arT, int* __restrict__ idxout, float* __restrict__ vals)
{
    const int b = blockIdx.y, r = blockIdx.x;
    __shared__ float pdot[4][64];
    __shared__ float Gs[4][256];
    __shared__ float Hs[4];
    __shared__ int gsh;
    __shared__ float Ys[49][260];      // stride 260: conflict-free b128 reads
    const int tid = threadIdx.x, w = tid >> 6, lane = tid & 63;

    // A: partial a_r dots — warp w covers c-chunk w
    {
        const float* qcol = qr + b*C*64 + r;
        const float* kcol = kr + b*C*64 + lane;
        float d = 0.f;
        #pragma unroll 8
        for (int cc = 0; cc < 64; cc++) {
            const int c = w*64 + cc;
            d += qcol[c*64] * kcol[c*64];
        }
        pdot[w][lane] = d;
    }
    // load G row t=w into LDS (coalesced float4)
    *(float4*)&Gs[w][lane*4] = *(const float4*)(G + ((b*256 + r*4 + w)*256) + lane*4);
    // H[w] = sum_c xg[b][c][r*4+w]*v2[c] + c0
    {
        const int pos = r*4 + w;
        float acc = 0.f;
        #pragma unroll
        for (int cc = 0; cc < 4; cc++) {
            const int c = lane + cc*64;
            acc += xg[(b*256 + c)*256 + pos] * v2[c];
        }
        #pragma unroll
        for (int off = 32; off >= 1; off >>= 1) acc += __shfl_xor(acc, off);
        if (lane == 0) Hs[w] = acc + c0p[0];
    }
    __syncthreads();

    // B: warp 0 — total dot, arT write, top-4 (low-index tie-break)
    if (w == 0) {
        const float dot = pdot[0][lane] + pdot[1][lane] + pdot[2][lane] + pdot[3][lane];
        arT[(b*64 + lane)*64 + r] = dot * SCALE;
        float v = dot;
        const int my = lane;
        #pragma unroll
        for (int t = 0; t < NTOPK; t++) {
            float bv = v; int bi = my;
            #pragma unroll
            for (int off = 32; off >= 1; off >>= 1) {
                const float ov = __shfl_xor(bv, off);
                const int   oi = __shfl_xor(bi, off);
                if (ov > bv || (ov == bv && oi < bi)) { bv = ov; bi = oi; }
            }
            if (lane == 0) {
                idxout[(b*64 + r)*NTOPK + t] = bi;
                if (t == NTOPK-1) gsh = bi;
            }
            if (my == bi) v = -3.0e38f;
        }
    }
    __syncthreads();

    // C: stage y region g into LDS as [k2][c]
    const int g = gsh;
    const int gy = g >> 3, gx = g & 7;
    if (tid < 245) {
        const int c5 = tid / 49, k2 = tid % 49;
        const int dy = d7(k2), dx = k2 - dy*7;
        const int kY = gy*7 + dy, kX = gx*7 + dx;
        const bool ok = (kY < HW) && (kX < HW);
        const float* srcp = y + (size_t)(b*256)*P + kY*HW + kX;
        for (int c = c5; c < 256; c += 5)
            Ys[k2][c] = ok ? srcp[(size_t)c*P] : 0.f;
    }
    __syncthreads();

    // E: vals[b,r,t,k2] = SCALE*(G_row . y_col + H)
    if (tid < NTOPK*49) {
        const int t = tid / 49, k2 = tid % 49;
        const int qX = (r & 7)*7 + t;
        const int dy = d7(k2), dx = k2 - dy*7;
        const int kY = gy*7 + dy, kX = gx*7 + dx;
        float res = 0.f;
        if (qX < HW && kY < HW && kX < HW) {
            const float4* Gp = (const float4*)&Gs[t][0];
            const float4* Yp = (const float4*)&Ys[k2][0];
            float dot = 0.f;
            #pragma unroll 8
            for (int cc = 0; cc < 64; cc++) {
                const float4 a = Gp[cc], yy = Yp[cc];
                dot += a.x*yy.x + a.y*yy.y + a.z*yy.z + a.w*yy.w;
            }
            res = SCALE * (dot + Hs[t]);
        }
        vals[((b*64 + r)*NTOPK + t)*49 + k2] = res;
    }
}

// ============ K4: final fill — one block per (b, Y1, X1) =====================
__global__ __launch_bounds__(256) void fill_kernel(
    const float* __restrict__ arT, const float* __restrict__ vals,
    const int* __restrict__ idx, float* __restrict__ out)
{
    const int b = blockIdx.y;
    const int yx = blockIdx.x;            // Y1*52 + X1
    const int Y1 = yx / HW, X1 = yx % HW;
    const int r1 = (Y1/7)*8 + X1/7;
    const int q1 = (Y1%7)*7 + X1%7;
    const int p2 = r1*49 + q1;
    const int yy = p2/56, xx = p2 - 56*yy;
    const int regB = (yy/7)*8 + xx/7;

    __shared__ float acol[64];
    __shared__ float vrow[49];
    const int tid = threadIdx.x;
    if (tid < 64) acol[tid] = arT[(b*64 + regB)*64 + tid];
    int ovr = -1;
    if (q1 < NTOPK) {
        ovr = idx[(b*64 + r1)*NTOPK + q1];
        if (tid < 49) vrow[tid] = vals[((b*64 + r1)*NTOPK + q1)*49 + tid];
    }
    __syncthreads();

    float* plane = out + (size_t)(b*P + yx) * P;
    for (int u = tid; u < 676; u += 256) {       // 676 = 52*13 float4 groups
        const int Y2 = d13(u);
        const int g4 = u - Y2*13;
        const int X2b = g4*4;
        const int ry2 = d7(Y2);
        const int my2 = Y2 - ry2*7;
        float res[4];
        #pragma unroll
        for (int j = 0; j < 4; j++) {
            const int X2 = X2b + j;
            const int rx2 = d7(X2);
            const int mx2 = X2 - rx2*7;
            const int r2 = ry2*8 + rx2;
            const int k2 = my2*7 + mx2;
            const int P1 = r2*49 + k2;
            const int Yp = d56(P1);
            const int Xp = P1 - Yp*56;
            const int regA = d7(Yp)*8 + d7(Xp);
            float v = acol[regA];
            if (r2 == ovr) v = vrow[k2];
            res[j] = v;
        }
        float4 o; o.x = res[0]; o.y = res[1]; o.z = res[2]; o.w = res[3];
        *(float4*)(plane + Y2*HW + X2b) = o;
    }
}

extern "C" void kernel_launch(void* const* d_in, const int* in_sizes, int n_in,
                              void* d_out, int out_size, void* d_ws, size_t ws_size,
                              hipStream_t stream)
{
    const float* x  = (const float*)d_in[0];
    const float* y  = (const float*)d_in[1];
    const float* qw = (const float*)d_in[2];
    const float* qb = (const float*)d_in[3];
    const float* kw = (const float*)d_in[4];
    const float* kb = (const float*)d_in[5];
    float* out = (float*)d_out;

    // Large scratch at the front of d_out (~6.5 MB << 234 MB out buffer);
    // fully consumed before fill_kernel overwrites d_out.
    float* xr  = out;                 // 8*256*64  = 131072
    float* yr  = xr + 131072;
    float* qr  = yr + 131072;
    float* kr  = qr + 131072;
    float* xg  = kr + 131072;         // 8*256*256 = 524288  [b][c][pos]
    float* G   = xg + 524288;         // 8*256*256 = 524288  [b][pos][o]
    float* M   = G  + 524288;         // 256*256
    float* u   = M  + 65536;          // 256
    float* v2  = u  + 256;            // 256
    float* c0p = v2 + 256;            // 1 (+pad)

    // fill-consumed small arrays stay in d_ws
    float* ws  = (float*)d_ws;
    float* arT = ws;                          // 8*64*64 = 32768
    float* vls = arT + 32768;                 // 8*64*4*49 = 100352
    int*   idx = (int*)(vls + 100352);        // 8*64*4 ints

    k1_pool_prep<<<1089, 256, 0, stream>>>(x, y, qw, qb, kw, kb, xr, yr, xg, M, u, v2, c0p);
    k2_gemms<<<192, 256, 0, stream>>>(xr, yr, qw, qb, kw, kb, qr, kr, xg, M, u, G);
    k3_topk_vals<<<dim3(64, 8), 256, 0, stream>>>(y, qr, kr, G, xg, v2, c0p, arT, idx, vls);
    fill_kernel<<<dim3(P, 8), 256, 0, stream>>>(arT, vls, idx, out);
}

// Round 4
// 112.586 us; speedup vs baseline: 1.5951x; 1.0293x over previous
//
#include <hip/hip_runtime.h>

#define NB 8
#define C 256
#define HW 52
#define P (HW*HW)            // 2704
#define NREG 64
#define NTOPK 4
#define SCALE 0.0625f

// exact unsigned div helpers (verified ranges)
static __device__ __forceinline__ int d7(int v)  { return (v*9363) >> 16; }   // v <= 3135
static __device__ __forceinline__ int d56(int v) { return (v*18725) >> 20; }  // v <= 3135
static __device__ __forceinline__ int d13(int v) { return (v*10083) >> 17; }  // v <= 675

// ============ K1: blocks 0..1023 pool+gather; 1024..1088 prep (M,u,v2,c0);
//              1089..2464 y NCHW->N(HW)C transpose into yT ==================
__global__ __launch_bounds__(256) void k1_pool_prep_tr(
    const float* __restrict__ x, const float* __restrict__ y,
    const float* __restrict__ qw, const float* __restrict__ qb,
    const float* __restrict__ kw, const float* __restrict__ kb,
    float* __restrict__ xr, float* __restrict__ yr, float* __restrict__ xg,
    float* __restrict__ M, float* __restrict__ u, float* __restrict__ v2,
    float* __restrict__ c0p, float* __restrict__ yT)
{
    __shared__ float sm[4*P];           // 43.3 KB
    const int tid = threadIdx.x;
    const int bx = blockIdx.x;

    if (bx >= 1089) {                   // ---- transpose path: 64c x 64pos tile ----
        const int tb = bx - 1089;
        const int b = tb / 172;
        const int rem = tb - b*172;
        const int ct = rem / 43;
        const int pt = rem - ct*43;
        const int c0 = ct*64, pos0 = pt*64;
        float* tile = sm;               // [64][65]
        const float* ysrc = y + ((size_t)(b*256 + c0))*P;
        #pragma unroll
        for (int p = 0; p < 4; p++) {
            const int cr = p*16 + (tid>>4);
            const int f4 = tid&15;
            const int pos = pos0 + f4*4;
            if (pos < P) {
                const float4 v = *(const float4*)(ysrc + (size_t)cr*P + pos);
                float* d = tile + cr*65 + f4*4;
                d[0]=v.x; d[1]=v.y; d[2]=v.z; d[3]=v.w;
            }
        }
        __syncthreads();
        #pragma unroll
        for (int p = 0; p < 4; p++) {
            const int pj = p*16 + (tid>>4);
            const int c4 = tid&15;
            const int pos = pos0 + pj;
            if (pos < P) {
                float4 v;
                v.x = tile[(c4*4+0)*65 + pj];
                v.y = tile[(c4*4+1)*65 + pj];
                v.z = tile[(c4*4+2)*65 + pj];
                v.w = tile[(c4*4+3)*65 + pj];
                *(float4*)(yT + ((size_t)(b*P + pos))*256 + c0 + c4*4) = v;
            }
        }
        return;
    }

    if (bx >= 1024) {                   // ---- prep path ----
        const int pb = bx - 1024;
        if (pb == 64) {
            float ua = 0.f, va = 0.f;
            for (int e = 0; e < 256; e++) {
                ua += qb[e] * kw[e*256 + tid];
                va += kb[e] * qw[e*256 + tid];
            }
            u[tid] = ua; v2[tid] = va;
            if (tid == 0) {
                float c = 0.f;
                for (int e = 0; e < 256; e++) c += qb[e]*kb[e];
                c0p[0] = c;
            }
            return;
        }
        const int cx0 = pb * 4;
        float (*wqs)[4] = (float(*)[4])sm;
        *(float4*)&wqs[tid][0] = *(const float4*)(qw + tid*256 + cx0);
        __syncthreads();
        float a0=0.f, a1=0.f, a2=0.f, a3=0.f;
        #pragma unroll 4
        for (int o = 0; o < 256; o++) {
            const float wk = kw[o*256 + tid];
            const float4 wq = *(const float4*)&wqs[o][0];
            a0 += wq.x*wk; a1 += wq.y*wk; a2 += wq.z*wk; a3 += wq.w*wk;
        }
        M[(cx0+0)*256 + tid] = a0;
        M[(cx0+1)*256 + tid] = a1;
        M[(cx0+2)*256 + tid] = a2;
        M[(cx0+3)*256 + tid] = a3;
        return;
    }

    // ---- pool path: wave w handles plane bx*4+w ----
    const int w = tid >> 6, lane = tid & 63;
    const int pl = bx*4 + w;
    const int proj = pl >> 11;
    const int bcid = pl & 2047;                     // b*256 + c
    const float* src = (proj ? y : x) + (size_t)bcid * P;
    float* plane = sm + w*P;
    {   // vectorized plane load: 676 float4
        const float4* s4 = (const float4*)src;
        float4* p4 = (float4*)plane;
        for (int g = lane; g < 676; g += 64) p4[g] = s4[g];
    }
    __syncthreads();
    const int jh = lane >> 3, jw = lane & 7;
    const int y0 = jh*7, x0 = jw*7;
    const int ry = min(7, HW - y0), rx = min(7, HW - x0);
    float s = 0.f;
    for (int dy = 0; dy < ry; ++dy) {
        const float* row = plane + (y0 + dy)*HW + x0;
        for (int dx = 0; dx < rx; ++dx) s += row[dx];
    }
    (proj ? yr : xr)[bcid*64 + lane] = s / (float)(ry*rx);
    if (!proj) {
        const float* r0 = plane + y0*HW + x0;
        float4 g4;
        g4.x = r0[0]; g4.y = r0[1]; g4.z = r0[2];
        g4.w = (x0 + 3 < HW) ? r0[3] : 0.f;
        *(float4*)&xg[bcid*256 + lane*4] = g4;
    }
}

// ============ K2: blocks 0..63 qkr_gemm; blocks 64..191 g_gemm ==============
__global__ __launch_bounds__(256) void k2_gemms(
    const float* __restrict__ xr, const float* __restrict__ yr,
    const float* __restrict__ qw, const float* __restrict__ qb,
    const float* __restrict__ kw, const float* __restrict__ kb,
    float* __restrict__ qr, float* __restrict__ kr,
    const float* __restrict__ xg, const float* __restrict__ M,
    const float* __restrict__ u, float* __restrict__ G)
{
    __shared__ float As[32][64];
    __shared__ float Bs[32][64];
    const int tid = threadIdx.x;
    const int tx = tid & 15, ty = tid >> 4;

    float acc[4][4];
    #pragma unroll
    for (int i = 0; i < 4; i++)
        #pragma unroll
        for (int j = 0; j < 4; j++) acc[i][j] = 0.f;

    if (blockIdx.x < 64) {
        // ---- qkr: O[o][j] = sum_k W[o][k]*X[k][j] + b[o] ----
        const int bp = blockIdx.x >> 2;
        const int b = bp >> 1, proj = bp & 1;
        const float* X = (proj ? yr : xr) + b*C*64;
        const float* W = proj ? kw : qw;
        const float* Bv = proj ? kb : qb;
        float* O = (proj ? kr : qr) + b*C*64;
        const int o0 = (blockIdx.x & 3) * 64;

        const int aor = tid & 63;
        const int akc = (tid >> 6) * 8;
        const int bkr = tid >> 3;
        const int bjc = (tid & 7) * 8;

        for (int k0 = 0; k0 < 256; k0 += 32) {
            const float4 w0 = *(const float4*)(W + (o0 + aor)*256 + k0 + akc);
            const float4 w1 = *(const float4*)(W + (o0 + aor)*256 + k0 + akc + 4);
            const float4 x0v = *(const float4*)(X + (k0 + bkr)*64 + bjc);
            const float4 x1v = *(const float4*)(X + (k0 + bkr)*64 + bjc + 4);
            __syncthreads();
            As[akc+0][aor] = w0.x; As[akc+1][aor] = w0.y; As[akc+2][aor] = w0.z; As[akc+3][aor] = w0.w;
            As[akc+4][aor] = w1.x; As[akc+5][aor] = w1.y; As[akc+6][aor] = w1.z; As[akc+7][aor] = w1.w;
            *(float4*)&Bs[bkr][bjc] = x0v;
            *(float4*)&Bs[bkr][bjc+4] = x1v;
            __syncthreads();
            #pragma unroll
            for (int kk = 0; kk < 32; kk++) {
                const float4 a = *(const float4*)&As[kk][ty*4];
                const float4 bb = *(const float4*)&Bs[kk][tx*4];
                const float av[4] = {a.x, a.y, a.z, a.w};
                const float bv[4] = {bb.x, bb.y, bb.z, bb.w};
                #pragma unroll
                for (int i = 0; i < 4; i++)
                    #pragma unroll
                    for (int j = 0; j < 4; j++) acc[i][j] += av[i]*bv[j];
            }
        }
        #pragma unroll
        for (int i = 0; i < 4; i++) {
            const int o = o0 + ty*4 + i;
            const float bias = Bv[o];
            float4 ov;
            ov.x = acc[i][0]+bias; ov.y = acc[i][1]+bias;
            ov.z = acc[i][2]+bias; ov.w = acc[i][3]+bias;
            *(float4*)(O + o*64 + tx*4) = ov;
        }
    } else {
        // ---- G[b][pos][o] = sum_c xg[b][c][pos]*M[c][o] + u[o] ----
        const int id2 = blockIdx.x - 64;
        const int b = id2 >> 4, sub = id2 & 15;
        const int p0 = (sub >> 2)*64, o0 = (sub & 3)*64;
        const float* Xg = xg + b*C*256;
        float* Gb = G + b*256*256;

        const int lkr = tid >> 3;
        const int ljc = (tid & 7) * 8;

        for (int k0 = 0; k0 < 256; k0 += 32) {
            const float4 a0 = *(const float4*)(Xg + (k0 + lkr)*256 + p0 + ljc);
            const float4 a1 = *(const float4*)(Xg + (k0 + lkr)*256 + p0 + ljc + 4);
            const float4 b0 = *(const float4*)(M + (k0 + lkr)*256 + o0 + ljc);
            const float4 b1 = *(const float4*)(M + (k0 + lkr)*256 + o0 + ljc + 4);
            __syncthreads();
            *(float4*)&As[lkr][ljc] = a0; *(float4*)&As[lkr][ljc+4] = a1;
            *(float4*)&Bs[lkr][ljc] = b0; *(float4*)&Bs[lkr][ljc+4] = b1;
            __syncthreads();
            #pragma unroll
            for (int kk = 0; kk < 32; kk++) {
                const float4 a = *(const float4*)&As[kk][ty*4];
                const float4 bb = *(const float4*)&Bs[kk][tx*4];
                const float av[4] = {a.x, a.y, a.z, a.w};
                const float bv[4] = {bb.x, bb.y, bb.z, bb.w};
                #pragma unroll
                for (int i = 0; i < 4; i++)
                    #pragma unroll
                    for (int j = 0; j < 4; j++) acc[i][j] += av[i]*bv[j];
            }
        }
        const float4 u4 = *(const float4*)(u + o0 + tx*4);
        #pragma unroll
        for (int i = 0; i < 4; i++) {
            float4 ov;
            ov.x = acc[i][0]+u4.x; ov.y = acc[i][1]+u4.y;
            ov.z = acc[i][2]+u4.z; ov.w = acc[i][3]+u4.w;
            *(float4*)(Gb + (p0 + ty*4 + i)*256 + o0 + tx*4) = ov;
        }
    }
}

// ============ K3: per (b,r): a_r row + top-4 + vals (coalesced yT stage) ====
__global__ __launch_bounds__(256) void k3_topk_vals(
    const float* __restrict__ yT, const float* __restrict__ qr,
    const float* __restrict__ kr, const float* __restrict__ G,
    const float* __restrict__ xg, const float* __restrict__ v2,
    const float* __restrict__ c0p,
    float* __restrict__ arT, int* __restrict__ idxout, float* __restrict__ vals)
{
    const int b = blockIdx.y, r = blockIdx.x;
    __shared__ float pdot[4][64];
    __shared__ float Gs[4][256];
    __shared__ float Hs[4];
    __shared__ int gsh;
    __shared__ float Ys[49][260];      // stride 260 floats
    const int tid = threadIdx.x, w = tid >> 6, lane = tid & 63;

    // A: partial a_r dots — warp w covers c-chunk w
    {
        const float* qcol = qr + b*C*64 + r;
        const float* kcol = kr + b*C*64 + lane;
        float d = 0.f;
        #pragma unroll 8
        for (int cc = 0; cc < 64; cc++) {
            const int c = w*64 + cc;
            d += qcol[c*64] * kcol[c*64];
        }
        pdot[w][lane] = d;
    }
    // load G row t=w into LDS (coalesced float4)
    *(float4*)&Gs[w][lane*4] = *(const float4*)(G + ((b*256 + r*4 + w)*256) + lane*4);
    // H[w] = sum_c xg[b][c][r*4+w]*v2[c] + c0
    {
        const int pos = r*4 + w;
        float acc = 0.f;
        #pragma unroll
        for (int cc = 0; cc < 4; cc++) {
            const int c = lane + cc*64;
            acc += xg[(b*256 + c)*256 + pos] * v2[c];
        }
        #pragma unroll
        for (int off = 32; off >= 1; off >>= 1) acc += __shfl_xor(acc, off);
        if (lane == 0) Hs[w] = acc + c0p[0];
    }
    __syncthreads();

    // B: warp 0 — total dot, arT write, top-4 (low-index tie-break)
    if (w == 0) {
        const float dot = pdot[0][lane] + pdot[1][lane] + pdot[2][lane] + pdot[3][lane];
        arT[(b*64 + lane)*64 + r] = dot * SCALE;
        float v = dot;
        const int my = lane;
        #pragma unroll
        for (int t = 0; t < NTOPK; t++) {
            float bv = v; int bi = my;
            #pragma unroll
            for (int off = 32; off >= 1; off >>= 1) {
                const float ov = __shfl_xor(bv, off);
                const int   oi = __shfl_xor(bi, off);
                if (ov > bv || (ov == bv && oi < bi)) { bv = ov; bi = oi; }
            }
            if (lane == 0) {
                idxout[(b*64 + r)*NTOPK + t] = bi;
                if (t == NTOPK-1) gsh = bi;
            }
            if (my == bi) v = -3.0e38f;
        }
    }
    __syncthreads();

    // C: stage yT rows for region g into LDS [k2][c] — coalesced float4
    const int g = gsh;
    const int gy = g >> 3, gx = g & 7;
    for (int i = tid; i < 49*64; i += 256) {
        const int k2 = i >> 6, f4 = i & 63;
        const int dy = d7(k2), dx = k2 - dy*7;
        const int kY = gy*7 + dy, kX = gx*7 + dx;
        float4 v = make_float4(0.f, 0.f, 0.f, 0.f);
        if (kY < HW && kX < HW)
            v = *(const float4*)(yT + ((size_t)(b*P + kY*HW + kX))*256 + f4*4);
        *(float4*)&Ys[k2][f4*4] = v;
    }
    __syncthreads();

    // E: vals[b,r,t,k2] = SCALE*(G_row . y_col + H)
    if (tid < NTOPK*49) {
        const int t = tid / 49, k2 = tid % 49;
        const int qX = (r & 7)*7 + t;
        const int dy = d7(k2), dx = k2 - dy*7;
        const int kY = gy*7 + dy, kX = gx*7 + dx;
        float res = 0.f;
        if (qX < HW && kY < HW && kX < HW) {
            const float4* Gp = (const float4*)&Gs[t][0];
            const float4* Yp = (const float4*)&Ys[k2][0];
            float dot = 0.f;
            #pragma unroll 8
            for (int cc = 0; cc < 64; cc++) {
                const float4 a = Gp[cc], yy = Yp[cc];
                dot += a.x*yy.x + a.y*yy.y + a.z*yy.z + a.w*yy.w;
            }
            res = SCALE * (dot + Hs[t]);
        }
        vals[((b*64 + r)*NTOPK + t)*49 + k2] = res;
    }
}

// ============ K4: final fill — one block per (b, Y1, X1) =====================
__global__ __launch_bounds__(256) void fill_kernel(
    const float* __restrict__ arT, const float* __restrict__ vals,
    const int* __restrict__ idx, float* __restrict__ out)
{
    const int b = blockIdx.y;
    const int yx = blockIdx.x;            // Y1*52 + X1
    const int Y1 = yx / HW, X1 = yx % HW;
    const int r1 = (Y1/7)*8 + X1/7;
    const int q1 = (Y1%7)*7 + X1%7;
    const int p2 = r1*49 + q1;
    const int yy = p2/56, xx = p2 - 56*yy;
    const int regB = (yy/7)*8 + xx/7;

    __shared__ float acol[64];
    __shared__ float vrow[49];
    const int tid = threadIdx.x;
    if (tid < 64) acol[tid] = arT[(b*64 + regB)*64 + tid];
    int ovr = -1;
    if (q1 < NTOPK) {
        ovr = idx[(b*64 + r1)*NTOPK + q1];
        if (tid < 49) vrow[tid] = vals[((b*64 + r1)*NTOPK + q1)*49 + tid];
    }
    __syncthreads();

    float* plane = out + (size_t)(b*P + yx) * P;
    for (int u = tid; u < 676; u += 256) {       // 676 = 52*13 float4 groups
        const int Y2 = d13(u);
        const int g4 = u - Y2*13;
        const int X2b = g4*4;
        const int ry2 = d7(Y2);
        const int my2 = Y2 - ry2*7;
        float res[4];
        #pragma unroll
        for (int j = 0; j < 4; j++) {
            const int X2 = X2b + j;
            const int rx2 = d7(X2);
            const int mx2 = X2 - rx2*7;
            const int r2 = ry2*8 + rx2;
            const int k2 = my2*7 + mx2;
            const int P1 = r2*49 + k2;
            const int Yp = d56(P1);
            const int Xp = P1 - Yp*56;
            const int regA = d7(Yp)*8 + d7(Xp);
            float v = acol[regA];
            if (r2 == ovr) v = vrow[k2];
            res[j] = v;
        }
        float4 o; o.x = res[0]; o.y = res[1]; o.z = res[2]; o.w = res[3];
        *(float4*)(plane + Y2*HW + X2b) = o;
    }
}

extern "C" void kernel_launch(void* const* d_in, const int* in_sizes, int n_in,
                              void* d_out, int out_size, void* d_ws, size_t ws_size,
                              hipStream_t stream)
{
    const float* x  = (const float*)d_in[0];
    const float* y  = (const float*)d_in[1];
    const float* qw = (const float*)d_in[2];
    const float* qb = (const float*)d_in[3];
    const float* kw = (const float*)d_in[4];
    const float* kb = (const float*)d_in[5];
    float* out = (float*)d_out;

    // Large scratch at the front of d_out (~28.7 MB << 234 MB out buffer);
    // fully consumed before fill_kernel overwrites d_out.
    float* xr  = out;                 // 8*256*64  = 131072
    float* yr  = xr + 131072;
    float* qr  = yr + 131072;
    float* kr  = qr + 131072;
    float* xg  = kr + 131072;         // 8*256*256 = 524288  [b][c][pos]
    float* G   = xg + 524288;         // 8*256*256 = 524288  [b][pos][o]
    float* M   = G  + 524288;         // 256*256
    float* u   = M  + 65536;          // 256
    float* v2  = u  + 256;            // 256
    float* c0p = v2 + 256;            // 16 (pad)
    float* yT  = c0p + 16;            // 8*2704*256 = 5537792  [b][pos][c]

    // fill-consumed small arrays stay in d_ws
    float* ws  = (float*)d_ws;
    float* arT = ws;                          // 8*64*64 = 32768
    float* vls = arT + 32768;                 // 8*64*4*49 = 100352
    int*   idx = (int*)(vls + 100352);        // 8*64*4 ints

    k1_pool_prep_tr<<<2465, 256, 0, stream>>>(x, y, qw, qb, kw, kb, xr, yr, xg,
                                              M, u, v2, c0p, yT);
    k2_gemms<<<192, 256, 0, stream>>>(xr, yr, qw, qb, kw, kb, qr, kr, xg, M, u, G);
    k3_topk_vals<<<dim3(64, 8), 256, 0, stream>>>(yT, qr, kr, G, xg, v2, c0p, arT, idx, vls);
    fill_kernel<<<dim3(P, 8), 256, 0, stream>>>(arT, vls, idx, out);
}